// Round 6
// baseline (439.170 us; speedup 1.0000x reference)
//
#include <hip/hip_runtime.h>
#include <hip/hip_bf16.h>
#include <math.h>

typedef __hip_bfloat16 bf16;

#define NPIX 4096

__device__ __forceinline__ float b2f(bf16 v) { return __bfloat162float(v); }

__device__ __forceinline__ unsigned short f2bu(float f) {
    bf16 h = __float2bfloat16(f);
    return *(unsigned short*)&h;
}

// Wave-inline dtype detector: true if buffer is bf16. Uniform per wave.
__device__ __forceinline__ int detect_bf16(const unsigned short* __restrict__ qraw) {
    int lane = threadIdx.x & 63;
    unsigned short u = qraw[lane * 2];
    int e = (u >> 7) & 0xFF;
    unsigned long long ball = __ballot(e >= 100 && e <= 135);
    return __popcll(ball) > 32;
}

// 2-pixel / 4-pixel activation loaders (fp32 or bf16 source)
__device__ __forceinline__ float2 ld2f(const float* __restrict__ p) { return *(const float2*)p; }
__device__ __forceinline__ float2 ld2f(const bf16* __restrict__ p) {
    unsigned u = *(const unsigned*)p;
    return make_float2(__uint_as_float(u << 16), __uint_as_float(u & 0xFFFF0000u));
}
__device__ __forceinline__ float4 ld4f(const float* __restrict__ p) { return *(const float4*)p; }
__device__ __forceinline__ float4 ld4f(const bf16* __restrict__ p) {
    uint2 u = *(const uint2*)p;
    return make_float4(__uint_as_float(u.x << 16), __uint_as_float(u.x & 0xFFFF0000u),
                       __uint_as_float(u.y << 16), __uint_as_float(u.y & 0xFFFF0000u));
}

// dot of 12 bf16 (24B, 8B-aligned) with qv[12]
__device__ __forceinline__ float dot12(const bf16* __restrict__ row, const float* qv) {
    const uint2* s = (const uint2*)row;
    float d = 0.f;
#pragma unroll
    for (int c = 0; c < 3; ++c) {
        uint2 u = s[c];
        d += qv[c * 4 + 0] * __uint_as_float(u.x << 16);
        d += qv[c * 4 + 1] * __uint_as_float(u.x & 0xFFFF0000u);
        d += qv[c * 4 + 2] * __uint_as_float(u.y << 16);
        d += qv[c * 4 + 3] * __uint_as_float(u.y & 0xFFFF0000u);
    }
    return d;
}

__device__ __forceinline__ void acc12(float* ov, const bf16* __restrict__ row, float f) {
    const uint2* s = (const uint2*)row;
#pragma unroll
    for (int c = 0; c < 3; ++c) {
        uint2 u = s[c];
        ov[c * 4 + 0] += f * __uint_as_float(u.x << 16);
        ov[c * 4 + 1] += f * __uint_as_float(u.x & 0xFFFF0000u);
        ov[c * 4 + 2] += f * __uint_as_float(u.y << 16);
        ov[c * 4 + 3] += f * __uint_as_float(u.y & 0xFFFF0000u);
    }
}

// ---------------- convert 26 small tensors to fp32 ----------------
struct CArgs {
    const void* src[26];
    int dstoff[26];
    int n[26];
};

__global__ void convert_kernel(CArgs a, const unsigned short* __restrict__ qraw,
                               float* __restrict__ cw)
{
    const int isbf = detect_bf16(qraw);
    const int t = blockIdx.y;
    const int n = a.n[t];
    float* d = cw + a.dstoff[t];
    if (isbf) {
        const bf16* s = (const bf16*)a.src[t];
        for (int i = blockIdx.x * 256 + threadIdx.x; i < n; i += 256 * gridDim.x) d[i] = b2f(s[i]);
    } else {
        const float* s = (const float*)a.src[t];
        for (int i = blockIdx.x * 256 + threadIdx.x; i < n; i += 256 * gridDim.x) d[i] = s[i];
    }
}

// ---------------- conv1: 1x1, 436 -> 64, virtual concat, lrelu, 2 och x 2 px ----------------
template <typename T>
__device__ __forceinline__ void conv1_body(const T* __restrict__ q, const T* __restrict__ v0,
                                           const T* __restrict__ v1, int pix0, int og,
                                           const float* __restrict__ w, float* acc)
{
    for (int i = 0; i < 144; ++i) {
        float2 a = ld2f(q + i * NPIX + pix0);
        float w0 = w[og * 436 + i], w1 = w[(og + 1) * 436 + i];
        acc[0] += a.x * w0; acc[1] += a.y * w0;
        acc[2] += a.x * w1; acc[3] += a.y * w1;
    }
    for (int i = 0; i < 144; ++i) {
        float2 a = ld2f(v0 + i * NPIX + pix0);
        float w0 = w[og * 436 + 144 + i], w1 = w[(og + 1) * 436 + 144 + i];
        acc[0] += a.x * w0; acc[1] += a.y * w0;
        acc[2] += a.x * w1; acc[3] += a.y * w1;
    }
    for (int i = 0; i < 144; ++i) {
        float2 a = ld2f(v1 + i * NPIX + pix0);
        float w0 = w[og * 436 + 288 + i], w1 = w[(og + 1) * 436 + 288 + i];
        acc[0] += a.x * w0; acc[1] += a.y * w0;
        acc[2] += a.x * w1; acc[3] += a.y * w1;
    }
}

__global__ void conv1_kernel(const void* __restrict__ q, const void* __restrict__ v0,
                             const void* __restrict__ v1, const float* __restrict__ fl0,
                             const float* __restrict__ fl1, const float* __restrict__ w,
                             const float* __restrict__ b, float* __restrict__ out)
{
    const int isbf = detect_bf16((const unsigned short*)q);
    const int og = blockIdx.y * 2;
    const int pix0 = (blockIdx.x * 256 + threadIdx.x) * 2;
    float acc[4] = { b[og], b[og], b[og + 1], b[og + 1] };
    if (isbf) conv1_body<bf16>((const bf16*)q, (const bf16*)v0, (const bf16*)v1, pix0, og, w, acc);
    else      conv1_body<float>((const float*)q, (const float*)v0, (const float*)v1, pix0, og, w, acc);
    float fa[8] = { fl0[pix0], fl0[pix0 + 1], fl0[NPIX + pix0], fl0[NPIX + pix0 + 1],
                    fl1[pix0], fl1[pix0 + 1], fl1[NPIX + pix0], fl1[NPIX + pix0 + 1] };
#pragma unroll
    for (int i = 0; i < 4; ++i) {
        float w0 = w[og * 436 + 432 + i], w1 = w[(og + 1) * 436 + 432 + i];
        acc[0] += fa[i * 2] * w0; acc[1] += fa[i * 2 + 1] * w0;
        acc[2] += fa[i * 2] * w1; acc[3] += fa[i * 2 + 1] * w1;
    }
#pragma unroll
    for (int j = 0; j < 2; ++j) {
        float vx = acc[j * 2], vy = acc[j * 2 + 1];
        vx = (vx >= 0.f) ? vx : 0.1f * vx;
        vy = (vy >= 0.f) ? vy : 0.1f * vy;
        *(float2*)(out + (og + j) * NPIX + pix0) = make_float2(vx, vy);
    }
}

// ---------------- conv 3x3, 64 -> 64, pad 1, lrelu, 2 och x 2 px ----------------
__global__ void conv3_kernel(const float* __restrict__ in, const float* __restrict__ w,
                             const float* __restrict__ b, float* __restrict__ out)
{
    const int og = blockIdx.y * 2;
    const int pix0 = (blockIdx.x * 256 + threadIdx.x) * 2;
    const int y = pix0 >> 6, x0 = pix0 & 63;          // x0 even, 0..62

    const float lm = (x0 > 0) ? 1.f : 0.f;
    const float rm = (x0 < 62) ? 1.f : 0.f;
    const int lo = max(x0 - 1, 0), ro = min(x0 + 2, 63);

    float rmask[3]; int roff[3];
#pragma unroll
    for (int r = 0; r < 3; ++r) {
        int yy = y + r - 1;
        rmask[r] = ((unsigned)yy < 64u) ? 1.f : 0.f;
        roff[r] = min(max(yy, 0), 63) * 64;
    }

    float a00 = b[og], a01 = b[og], a10 = b[og + 1], a11 = b[og + 1];
    for (int ci = 0; ci < 64; ++ci) {
        const float* ib = in + ci * NPIX;
        float win[3][4];
#pragma unroll
        for (int r = 0; r < 3; ++r) {
            const float* rp = ib + roff[r];
            float2 f = *(const float2*)(rp + x0);
            float rmk = rmask[r];
            win[r][0] = rp[lo] * lm * rmk;
            win[r][1] = f.x * rmk;
            win[r][2] = f.y * rmk;
            win[r][3] = rp[ro] * rm * rmk;
        }
        const float* w0 = w + og * 576 + ci * 9;
        const float* w1 = w0 + 576;
#pragma unroll
        for (int dy = 0; dy < 3; ++dy) {
#pragma unroll
            for (int dx = 0; dx < 3; ++dx) {
                float wt0 = w0[dy * 3 + dx], wt1 = w1[dy * 3 + dx];
                a00 += win[dy][dx] * wt0;     a01 += win[dy][dx + 1] * wt0;
                a10 += win[dy][dx] * wt1;     a11 += win[dy][dx + 1] * wt1;
            }
        }
    }
    a00 = (a00 >= 0.f) ? a00 : 0.1f * a00;
    a01 = (a01 >= 0.f) ? a01 : 0.1f * a01;
    a10 = (a10 >= 0.f) ? a10 : 0.1f * a10;
    a11 = (a11 >= 0.f) ? a11 : 0.1f * a11;
    *(float2*)(out + og * NPIX + pix0) = make_float2(a00, a01);
    *(float2*)(out + (og + 1) * NPIX + pix0) = make_float2(a10, a11);
}

// ---------------- conv6: 1x1, 64 -> 432, 10*tanh + flow + bases -> py/px, 8 out x 2 px ----------------
__global__ void conv6_off_kernel(const float* __restrict__ in, const float* __restrict__ w,
                                 const float* __restrict__ b, const float* __restrict__ fl0,
                                 float* __restrict__ py, float* __restrict__ px)
{
    const int obase = blockIdx.y * 8;
    const int pix0 = (blockIdx.x * 256 + threadIdx.x) * 2;
    float acc[16];
#pragma unroll
    for (int j = 0; j < 8; ++j) { acc[j * 2] = b[obase + j]; acc[j * 2 + 1] = b[obase + j]; }
    for (int i = 0; i < 64; ++i) {
        float2 a = *(const float2*)(in + i * NPIX + pix0);
#pragma unroll
        for (int j = 0; j < 8; ++j) {
            float wv = w[(obase + j) * 64 + i];
            acc[j * 2] += a.x * wv; acc[j * 2 + 1] += a.y * wv;
        }
    }
    const float fy0 = fl0[NPIX + pix0], fy1 = fl0[NPIX + pix0 + 1];
    const float fx0 = fl0[pix0], fx1 = fl0[pix0 + 1];
    const float yf = (float)(pix0 >> 6);
    const float xf0 = (float)(pix0 & 63), xf1 = xf0 + 1.f;
#pragma unroll
    for (int j = 0; j < 8; ++j) {
        int o = obase + j;
        float v0 = 10.f * tanhf(acc[j * 2]);
        float v1 = 10.f * tanhf(acc[j * 2 + 1]);
        int s = o >> 1;
        int a_idx = s % 9;
        if ((o & 1) == 0) {
            float base = (float)(a_idx / 3 - 1) + yf;
            *(float2*)(py + s * NPIX + pix0) = make_float2(v0 + fy0 + base, v1 + fy1 + base);
        } else {
            float base = (float)(a_idx % 3 - 1);
            *(float2*)(px + s * NPIX + pix0) = make_float2(v0 + fx0 + base + xf0, v1 + fx1 + base + xf1);
        }
    }
}

// ---------------- fused q/k/v projection: 5 z-slices, 8 out x 4 px ----------------
struct PS { const void* src; const float* w; const float* b; bf16* dst; int clip; };
struct PArgs { PS s[5]; };

template <typename T>
__device__ __forceinline__ void proj_body(const T* __restrict__ ib, int pix0, int og,
                                          const float* __restrict__ w, float* acc)
{
    for (int i = 0; i < 144; ++i) {
        float4 a = ld4f(ib + i * NPIX + pix0);
#pragma unroll
        for (int j = 0; j < 8; ++j) {
            float wv = w[i * 288 + og + j];
            acc[j * 4 + 0] += a.x * wv;
            acc[j * 4 + 1] += a.y * wv;
            acc[j * 4 + 2] += a.z * wv;
            acc[j * 4 + 3] += a.w * wv;
        }
    }
}

__global__ void proj_kernel(PArgs pa, const unsigned short* __restrict__ qraw)
{
    const int isbf = detect_bf16(qraw);
    const PS ps = pa.s[blockIdx.z];
    const int og = blockIdx.y * 8;          // never crosses a 24-boundary
    const int pix0 = (blockIdx.x * 256 + threadIdx.x) * 4;
    float acc[32];
#pragma unroll
    for (int j = 0; j < 8; ++j) {
        float bv = ps.b[og + j];
        acc[j * 4] = bv; acc[j * 4 + 1] = bv; acc[j * 4 + 2] = bv; acc[j * 4 + 3] = bv;
    }
    if (isbf) proj_body<bf16>((const bf16*)ps.src + (size_t)ps.clip * 144 * NPIX, pix0, og, ps.w, acc);
    else      proj_body<float>((const float*)ps.src + (size_t)ps.clip * 144 * NPIX, pix0, og, ps.w, acc);
    const int g = og / 24, cj = og % 24;
#pragma unroll
    for (int px = 0; px < 4; ++px) {
        bf16* ob = ps.dst + ((size_t)(ps.clip * 12 + g) * NPIX + pix0 + px) * 24 + cj;
        uint4 u;
        u.x = ((unsigned)f2bu(acc[1 * 4 + px]) << 16) | f2bu(acc[0 * 4 + px]);
        u.y = ((unsigned)f2bu(acc[3 * 4 + px]) << 16) | f2bu(acc[2 * 4 + px]);
        u.z = ((unsigned)f2bu(acc[5 * 4 + px]) << 16) | f2bu(acc[4 * 4 + px]);
        u.w = ((unsigned)f2bu(acc[7 * 4 + px]) << 16) | f2bu(acc[6 * 4 + px]);
        *(uint4*)ob = u;
    }
}

// ---------------- deformable gather + attention, 4-thread teams ----------------
__global__ __launch_bounds__(256) void attn_kernel(
    const bf16* __restrict__ qp, const bf16* __restrict__ kp,
    const bf16* __restrict__ vp, const float* __restrict__ py,
    const float* __restrict__ px, bf16* __restrict__ att)
{
    const int t = blockIdx.x * 256 + threadIdx.x;
    const int ch = t & 1;
    const int clip = (t >> 1) & 1;
    const int pp = t >> 2;
    const int m = pp >> 12;
    const int p = pp & 4095;

    float qv[12];
    {
        const uint2* s = (const uint2*)(qp + (size_t)(m * 4096 + p) * 24 + ch * 12);
#pragma unroll
        for (int c = 0; c < 3; ++c) {
            uint2 u = s[c];
            qv[c * 4 + 0] = __uint_as_float(u.x << 16);
            qv[c * 4 + 1] = __uint_as_float(u.x & 0xFFFF0000u);
            qv[c * 4 + 2] = __uint_as_float(u.y << 16);
            qv[c * 4 + 3] = __uint_as_float(u.y & 0xFFFF0000u);
        }
    }

    const int gidx = clip * 12 + m;
    const bf16* kb = kp + (size_t)gidx * 4096 * 24 + ch * 12;
    const bf16* vb = vp + (size_t)gidx * 4096 * 24 + ch * 12;
    const int sbase = gidx * 9;

    float e[9];
    float mx = -1e30f;
#pragma unroll
    for (int a = 0; a < 9; ++a) {
        const float fy = py[(sbase + a) * NPIX + p];
        const float fx = px[(sbase + a) * NPIX + p];
        const float y0 = floorf(fy), x0 = floorf(fx);
        const float wy = fy - y0, wx = fx - x0;
        const int iy = (int)y0, ix = (int)x0;
        const float w00 = (1.f - wy) * (1.f - wx), w01 = (1.f - wy) * wx;
        const float w10 = wy * (1.f - wx), w11 = wy * wx;
        float part = 0.f;
        if ((unsigned)iy < 64u) {
            const bf16* r = kb + (size_t)(iy * 64) * 24;
            if ((unsigned)ix < 64u)       part += w00 * dot12(r + ix * 24, qv);
            if ((unsigned)(ix + 1) < 64u) part += w01 * dot12(r + (ix + 1) * 24, qv);
        }
        if ((unsigned)(iy + 1) < 64u) {
            const bf16* r = kb + (size_t)((iy + 1) * 64) * 24;
            if ((unsigned)ix < 64u)       part += w10 * dot12(r + ix * 24, qv);
            if ((unsigned)(ix + 1) < 64u) part += w11 * dot12(r + (ix + 1) * 24, qv);
        }
        float full = part + __shfl_xor(part, 1, 64);
        e[a] = full * 0.20412414523193154f;   // 24^-0.5
        mx = fmaxf(mx, e[a]);
    }
    mx = fmaxf(mx, __shfl_xor(mx, 2, 64));
    float sum = 0.f;
#pragma unroll
    for (int a = 0; a < 9; ++a) { e[a] = __expf(e[a] - mx); sum += e[a]; }
    sum += __shfl_xor(sum, 2, 64);
    const float inv = 1.f / sum;

    float ov[12];
#pragma unroll
    for (int j = 0; j < 12; ++j) ov[j] = 0.f;

#pragma unroll
    for (int a = 0; a < 9; ++a) {
        const float wa = e[a] * inv;
        const float fy = py[(sbase + a) * NPIX + p];
        const float fx = px[(sbase + a) * NPIX + p];
        const float y0 = floorf(fy), x0 = floorf(fx);
        const float wy = fy - y0, wx = fx - x0;
        const int iy = (int)y0, ix = (int)x0;
        if ((unsigned)iy < 64u) {
            const bf16* r = vb + (size_t)(iy * 64) * 24;
            if ((unsigned)ix < 64u)       acc12(ov, r + ix * 24, wa * (1.f - wy) * (1.f - wx));
            if ((unsigned)(ix + 1) < 64u) acc12(ov, r + (ix + 1) * 24, wa * (1.f - wy) * wx);
        }
        if ((unsigned)(iy + 1) < 64u) {
            const bf16* r = vb + (size_t)((iy + 1) * 64) * 24;
            if ((unsigned)ix < 64u)       acc12(ov, r + ix * 24, wa * wy * (1.f - wx));
            if ((unsigned)(ix + 1) < 64u) acc12(ov, r + (ix + 1) * 24, wa * wy * wx);
        }
    }
#pragma unroll
    for (int j = 0; j < 12; ++j) ov[j] += __shfl_xor(ov[j], 2, 64);
    if (clip == 0) {
#pragma unroll
        for (int j = 0; j < 12; ++j)
            att[(size_t)(m * 24 + ch * 12 + j) * NPIX + p] = __float2bfloat16(ov[j]);
    }
}

// ---------------- generic channel-linear, 4 out x 2 px ----------------
template <typename TI, int CIN, int ACT>
__global__ void linear_kernel(const TI* __restrict__ in, const float* __restrict__ w,
                              const float* __restrict__ b, int cout, float* __restrict__ out)
{
    const int og = blockIdx.y * 4;
    const int pix0 = (blockIdx.x * 256 + threadIdx.x) * 2;
    float acc[8];
#pragma unroll
    for (int j = 0; j < 4; ++j) { acc[j * 2] = b[og + j]; acc[j * 2 + 1] = b[og + j]; }
    for (int i = 0; i < CIN; ++i) {
        float2 a = ld2f(in + i * NPIX + pix0);
#pragma unroll
        for (int j = 0; j < 4; ++j) {
            float wv = w[i * cout + og + j];
            acc[j * 2] += a.x * wv; acc[j * 2 + 1] += a.y * wv;
        }
    }
#pragma unroll
    for (int j = 0; j < 4; ++j) {
        float vx = acc[j * 2], vy = acc[j * 2 + 1];
        if (ACT == 1) {
            vx = 0.5f * vx * (1.f + erff(vx * 0.70710678118654752f));
            vy = 0.5f * vy * (1.f + erff(vy * 0.70710678118654752f));
        }
        *(float2*)(out + (og + j) * NPIX + pix0) = make_float2(vx, vy);
    }
}

// ---------------- final: m2 = linear(m1, wm2); out = o + m2 (dtype per flag), 4 out x 2 px ----------------
__global__ void final_kernel(const float* __restrict__ m1, const float* __restrict__ w,
                             const float* __restrict__ b, const float* __restrict__ o,
                             const unsigned short* __restrict__ qraw, void* __restrict__ outv)
{
    const int isbf = detect_bf16(qraw);
    const int og = blockIdx.y * 4;
    const int pix0 = (blockIdx.x * 256 + threadIdx.x) * 2;
    float acc[8];
#pragma unroll
    for (int j = 0; j < 4; ++j) { acc[j * 2] = b[og + j]; acc[j * 2 + 1] = b[og + j]; }
    for (int i = 0; i < 288; ++i) {
        float2 a = *(const float2*)(m1 + i * NPIX + pix0);
#pragma unroll
        for (int j = 0; j < 4; ++j) {
            float wv = w[i * 144 + og + j];
            acc[j * 2] += a.x * wv; acc[j * 2 + 1] += a.y * wv;
        }
    }
    if (isbf) {
        bf16* out = (bf16*)outv;
#pragma unroll
        for (int j = 0; j < 4; ++j) {
            float2 ov = *(const float2*)(o + (og + j) * NPIX + pix0);
            unsigned u = ((unsigned)f2bu(acc[j * 2 + 1] + ov.y) << 16) | f2bu(acc[j * 2] + ov.x);
            *(unsigned*)(out + (og + j) * NPIX + pix0) = u;
        }
    } else {
        float* out = (float*)outv;
#pragma unroll
        for (int j = 0; j < 4; ++j) {
            float2 ov = *(const float2*)(o + (og + j) * NPIX + pix0);
            *(float2*)(out + (og + j) * NPIX + pix0) =
                make_float2(acc[j * 2] + ov.x, acc[j * 2 + 1] + ov.y);
        }
    }
}

// ---------------- diagnostic ----------------
__global__ void diag_kernel(float* __restrict__ out, int n, float v)
{
    int i = blockIdx.x * 256 + threadIdx.x;
    if (i < n) out[i] = (i == 0 ? v : 0.f);
}

extern "C" void kernel_launch(void* const* d_in, const int* in_sizes, int n_in,
                              void* d_out, int out_size, void* d_ws, size_t ws_size,
                              hipStream_t stream)
{
    const size_t REQUIRED = 23115776;
    if (ws_size < REQUIRED) {
        float code = 1000.0f + (float)(ws_size >> 20);
        diag_kernel<<<dim3((out_size + 255) / 256), 256, 0, stream>>>((float*)d_out, out_size, code);
        return;
    }

    char* base = (char*)d_ws;
    float* cw    = (float*)(base + 64);
    float* py    = (float*)(base + 1882112);
    float* px    = (float*)(base + 5421056);
    bf16*  qp    = (bf16*) (base + 8960000);
    bf16*  kp    = (bf16*) (base + 11319296);
    bf16*  vp    = (bf16*) (base + 16037888);
    bf16*  att   = (bf16*) (base + 20756480);
    float* xA    = (float*)(base + 20756480);   // alias att (dead before attn)
    float* xB    = (float*)(base + 21805056);
    float* o     = (float*)(base + 8960000);    // alias qp (dead after attn)
    float* m1    = (float*)(base + 11319296);   // alias kp (dead after attn)

    const int OF_WO1 = 0,      OF_BO1 = 27904,  OF_WO2 = 27968,  OF_BO2 = 64832;
    const int OF_WO3 = 64896,  OF_BO3 = 101760, OF_WO4 = 101824, OF_BO4 = 138688;
    const int OF_WO5 = 138752, OF_BO5 = 175616, OF_WO6 = 175680, OF_BO6 = 203328;
    const int OF_WQ  = 203760, OF_BQ  = 245232, OF_WK  = 245520, OF_BK  = 286992;
    const int OF_WV  = 287280, OF_BV  = 328752, OF_WP  = 329040, OF_BP  = 370512;
    const int OF_WM1 = 370656, OF_BM1 = 412128, OF_WM2 = 412416, OF_BM2 = 453888;
    const int OF_FL0 = 454032, OF_FL1 = 462224;

    const unsigned short* qraw = (const unsigned short*)d_in[0];

    CArgs ca;
    const int srcidx[26] = {7,8,9,10,11,12,13,14,15,16,17,18,19,20,21,22,23,24,25,26,27,28,29,30,5,6};
    const int dsto[26]   = {OF_WO1,OF_BO1,OF_WO2,OF_BO2,OF_WO3,OF_BO3,OF_WO4,OF_BO4,OF_WO5,OF_BO5,
                            OF_WO6,OF_BO6,OF_WQ,OF_BQ,OF_WK,OF_BK,OF_WV,OF_BV,OF_WP,OF_BP,
                            OF_WM1,OF_BM1,OF_WM2,OF_BM2,OF_FL0,OF_FL1};
    for (int i = 0; i < 26; ++i) {
        ca.src[i] = d_in[srcidx[i]];
        ca.dstoff[i] = dsto[i];
        ca.n[i] = in_sizes[srcidx[i]];
    }
    convert_kernel<<<dim3(8, 26), 256, 0, stream>>>(ca, qraw, cw);

    conv1_kernel<<<dim3(8, 32), 256, 0, stream>>>(d_in[0], d_in[3], d_in[4],
                                                  cw + OF_FL0, cw + OF_FL1,
                                                  cw + OF_WO1, cw + OF_BO1, xA);
    conv3_kernel<<<dim3(8, 32), 256, 0, stream>>>(xA, cw + OF_WO2, cw + OF_BO2, xB);
    conv3_kernel<<<dim3(8, 32), 256, 0, stream>>>(xB, cw + OF_WO3, cw + OF_BO3, xA);
    conv3_kernel<<<dim3(8, 32), 256, 0, stream>>>(xA, cw + OF_WO4, cw + OF_BO4, xB);
    conv3_kernel<<<dim3(8, 32), 256, 0, stream>>>(xB, cw + OF_WO5, cw + OF_BO5, xA);
    conv6_off_kernel<<<dim3(8, 54), 256, 0, stream>>>(xA, cw + OF_WO6, cw + OF_BO6,
                                                      cw + OF_FL0, py, px);

    PArgs pa;
    pa.s[0] = { d_in[0], cw + OF_WQ, cw + OF_BQ, qp, 0 };
    pa.s[1] = { d_in[1], cw + OF_WK, cw + OF_BK, kp, 0 };
    pa.s[2] = { d_in[1], cw + OF_WK, cw + OF_BK, kp, 1 };
    pa.s[3] = { d_in[2], cw + OF_WV, cw + OF_BV, vp, 0 };
    pa.s[4] = { d_in[2], cw + OF_WV, cw + OF_BV, vp, 1 };
    proj_kernel<<<dim3(4, 36, 5), 256, 0, stream>>>(pa, qraw);

    attn_kernel<<<dim3(768), 256, 0, stream>>>(qp, kp, vp, py, px, att);

    linear_kernel<bf16, 288, 0><<<dim3(8, 36), 256, 0, stream>>>(att, cw + OF_WP, cw + OF_BP, 144, o);
    linear_kernel<float, 144, 1><<<dim3(8, 72), 256, 0, stream>>>(o, cw + OF_WM1, cw + OF_BM1, 288, m1);
    final_kernel<<<dim3(8, 36), 256, 0, stream>>>(m1, cw + OF_WM2, cw + OF_BM2, o, qraw, d_out);
}